// Round 2
// baseline (227.181 us; speedup 1.0000x reference)
//
#include <hip/hip_runtime.h>

// Problem constants
#define WF 512
#define HF 256
#define CF 64
#define NDTOT 65

static constexpr size_t CH  = (size_t)HF * WF;   // one channel plane (elements)
static constexpr size_t WH  = (size_t)HF * WF;   // one (b,d) output plane (elements)
static constexpr float  INV = 1.0f / 576.0f;     // 1/(K*K*C)

// Granule (16B) XOR swizzle: logical float index -> physical float index.
// Preserved by any 16B-aligned float4 access (granule stays intact).
__device__ __forceinline__ int swz(int i) {
    const int G = i >> 2;
    return ((G ^ ((G >> 3) & 7)) << 2) | (i & 3);
}

// ---------------------------------------------------------------------------
// k1: per (b, y) row — horizontally box-summed channel-dot rows.
//   r[d][x] = sum_{v=x-1..x+1} sum_c x0[b,c,y,v] * x1[b,c,y,v+d-32]
// Thread tile: 8 cols x 16(17) d.  t&63 = col-group g (cols 8g..8g+7, lane),
// t>>6 = d-group h (d = 16h+dd; h==3 takes dd=0..16 to cover d=64).
// x1 row staged in swizzled LDS (576 floats incl. +-32 shift pad);
// x0 held in registers (each thread loads its own 8 floats, L1-served).
// ---------------------------------------------------------------------------
__global__ __launch_bounds__(256, 2)
void corr_rows(const float* __restrict__ x0, const float* __restrict__ x1,
               float* __restrict__ ws, size_t wsBStride) {
    const int y = blockIdx.x;
    const int b = blockIdx.y;
    const int t = threadIdx.x;
    const int g = t & 63;          // col-group (lane)
    const int h = t >> 6;          // d-group (wave)
    const int nd = (h == 3) ? 17 : 16;

    __shared__ __align__(16) float lds1[576];   // lds1[i] = x1 col (i-32), OOB -> 0

    const float* x0row = x0 + (size_t)b * CF * CH + (size_t)y * WF;
    const float* x1row = x1 + (size_t)b * CF * CH + (size_t)y * WF;

    // Swizzled staging-write addresses (constant per thread).
    const int wa0 = swz(t);
    const int wa1 = swz(t + 256);
    const int wa2 = swz(t + 512);               // used iff t < 64
    // Swizzled read-granule base addresses: logical window starts at 8g+16h.
    int ra[6];
#pragma unroll
    for (int k = 0; k < 6; ++k) {
        const int G = 2 * g + 4 * h + k;
        ra[k] = (G ^ ((G >> 3) & 7)) << 2;
    }

    float acc[17][8];
#pragma unroll
    for (int dd = 0; dd < 17; ++dd)
#pragma unroll
        for (int xi = 0; xi < 8; ++xi) acc[dd][xi] = 0.f;

    // x1 staging columns for logical lds indices t, t+256, t+512
    const int c0 = t - 32;         // [-32, 223]
    const int c1 = t + 224;        // [224, 479] always valid
    const int c2 = t + 480;        // [480, 543] valid iff < 512

    // prefetch channel 0
    float v0 = (c0 >= 0) ? x1row[c0] : 0.f;
    float v1 = x1row[c1];
    float v2 = (t < 64 && c2 < WF) ? x1row[c2] : 0.f;
    float4 xa = *(const float4*)(x0row + 8 * g);
    float4 xb = *(const float4*)(x0row + 8 * g + 4);

#pragma unroll 1
    for (int c = 0; c < CF; ++c) {
        __syncthreads();                       // prior readers done
        lds1[wa0] = v0;
        lds1[wa1] = v1;
        if (t < 64) lds1[wa2] = v2;
        __syncthreads();                       // row c staged

        const float x0v[8] = {xa.x, xa.y, xa.z, xa.w, xb.x, xb.y, xb.z, xb.w};

        if (c + 1 < CF) {                      // prefetch next channel
            const float* xr = x1row + (size_t)(c + 1) * CH;
            v0 = (c0 >= 0) ? xr[c0] : 0.f;
            v1 = xr[c1];
            v2 = (t < 64 && c2 < WF) ? xr[c2] : 0.f;
            const float* x0n = x0row + (size_t)(c + 1) * CH + 8 * g;
            xa = *(const float4*)x0n;
            xb = *(const float4*)(x0n + 4);
        }

        // window floats L0..L0+23 (L0 = 8g+16h), via 6 swizzled ds_read_b128
        float w[24];
#pragma unroll
        for (int k = 0; k < 6; ++k) {
            const float4 r = *(const float4*)&lds1[ra[k]];
            w[4 * k + 0] = r.x; w[4 * k + 1] = r.y;
            w[4 * k + 2] = r.z; w[4 * k + 3] = r.w;
        }
#pragma unroll
        for (int dd = 0; dd < 17; ++dd) {
            if (dd < nd) {                     // wave-uniform
#pragma unroll
                for (int xi = 0; xi < 8; ++xi)
                    acc[dd][xi] = fmaf(x0v[xi], w[dd + xi], acc[dd][xi]);
            }
        }
    }

    // Horizontal 3-sum via intra-wave shuffles (col neighbors are lane +-1).
    float* wsb = ws + (size_t)b * wsBStride;
#pragma unroll
    for (int dd = 0; dd < 17; ++dd) {
        if (dd < nd) {                         // wave-uniform -> shfl safe
            float left  = __shfl_up(acc[dd][7], 1);
            if (g == 0)  left = 0.f;           // col -1 is zero-pad
            float right = __shfl_down(acc[dd][0], 1);
            if (g == 63) right = 0.f;          // col 512 is zero-pad
            float r[8];
            r[0] = left + acc[dd][0] + acc[dd][1];
#pragma unroll
            for (int xi = 1; xi < 7; ++xi)
                r[xi] = acc[dd][xi - 1] + acc[dd][xi] + acc[dd][xi + 1];
            r[7] = acc[dd][6] + acc[dd][7] + right;

            const int d = 16 * h + dd;
            float* dst = wsb + ((size_t)d * HF + y) * WF + 8 * g;
            *(float4*)dst       = make_float4(r[0], r[1], r[2], r[3]);
            *(float4*)(dst + 4) = make_float4(r[4], r[5], r[6], r[7]);
        }
    }
}

// ---------------------------------------------------------------------------
// k2: vertical 3-sum + scale: out[d][i][j] = INV * (r[i-1] + r[i] + r[i+1])
// grid: (8 rowgroups, D, B); block 256 = 2 chains x 128 float4-columns.
// ---------------------------------------------------------------------------
__global__ __launch_bounds__(256)
void corr_vsum(const float* __restrict__ ws, float* __restrict__ out,
               size_t wsBStride, size_t outBStride) {
    const int t = threadIdx.x;
    const int chain = t >> 7;             // 0,1
    const int j = (t & 127) * 4;
    const int r0 = blockIdx.x * 32 + chain * 16;
    const int d = blockIdx.y;
    const int b = blockIdx.z;

    const float* wp = ws + (size_t)b * wsBStride + (size_t)d * WH + j;
    float* op       = out + (size_t)b * outBStride + (size_t)d * WH + j;

    float4 prev, cur;
    if (r0 > 0) prev = *(const float4*)(wp + (size_t)(r0 - 1) * WF);
    else        prev = make_float4(0.f, 0.f, 0.f, 0.f);
    cur = *(const float4*)(wp + (size_t)r0 * WF);

#pragma unroll
    for (int i = 0; i < 16; ++i) {
        const int r = r0 + i;
        float4 nx;
        if (r + 1 < HF) nx = *(const float4*)(wp + (size_t)(r + 1) * WF);
        else            nx = make_float4(0.f, 0.f, 0.f, 0.f);
        float4 o;
        o.x = (prev.x + cur.x + nx.x) * INV;
        o.y = (prev.y + cur.y + nx.y) * INV;
        o.z = (prev.z + cur.z + nx.z) * INV;
        o.w = (prev.w + cur.w + nx.w) * INV;
        *(float4*)(op + (size_t)r * WF) = o;
        prev = cur; cur = nx;
    }
}

// ---------------------------------------------------------------------------
// Emergency fallback (tiny ws): direct computation, slow but correct.
// ---------------------------------------------------------------------------
__global__ void corr_naive(const float* __restrict__ x0, const float* __restrict__ x1,
                           float* __restrict__ out) {
    const size_t total = (size_t)4 * NDTOT * WH;
    size_t idx = (size_t)blockIdx.x * blockDim.x + threadIdx.x;
    if (idx >= total) return;
    const int j = (int)(idx % WF);
    const int i = (int)((idx / WF) % HF);
    const int d = (int)((idx / WH) % NDTOT);
    const int b = (int)(idx / ((size_t)NDTOT * WH));
    const int disp = d - 32;
    float s = 0.f;
    for (int u = i - 1; u <= i + 1; ++u) {
        if (u < 0 || u >= HF) continue;
        for (int v = j - 1; v <= j + 1; ++v) {
            if (v < 0 || v >= WF) continue;
            const int v1c = v + disp;
            if (v1c < 0 || v1c >= WF) continue;
            const float* p0 = x0 + (size_t)b * CF * CH + (size_t)u * WF + v;
            const float* p1 = x1 + (size_t)b * CF * CH + (size_t)u * WF + v1c;
            for (int c = 0; c < CF; ++c)
                s += p0[(size_t)c * CH] * p1[(size_t)c * CH];
        }
    }
    out[idx] = s * INV;
}

// ---------------------------------------------------------------------------
extern "C" void kernel_launch(void* const* d_in, const int* in_sizes, int n_in,
                              void* d_out, int out_size, void* d_ws, size_t ws_size,
                              hipStream_t stream) {
    const float* x0 = (const float*)d_in[0];
    const float* x1 = (const float*)d_in[1];
    float* out = (float*)d_out;
    float* ws  = (float*)d_ws;

    const size_t fullB = (size_t)NDTOT * WH;     // per-b ws elements

    if (ws_size >= 4 * fullB * sizeof(float)) {
        corr_rows<<<dim3(256, 4), dim3(256), 0, stream>>>(x0, x1, ws, fullB);
        corr_vsum<<<dim3(8, 65, 4), dim3(256), 0, stream>>>(ws, out, fullB, fullB);
    } else if (ws_size >= fullB * sizeof(float)) {
        for (int b = 0; b < 4; ++b) {
            const float* x0b = x0 + (size_t)b * CF * CH;
            const float* x1b = x1 + (size_t)b * CF * CH;
            float* outb = out + (size_t)b * fullB;
            corr_rows<<<dim3(256, 1), dim3(256), 0, stream>>>(x0b, x1b, ws, 0);
            corr_vsum<<<dim3(8, 65, 1), dim3(256), 0, stream>>>(ws, outb, 0, 0);
        }
    } else {
        const size_t total = (size_t)4 * NDTOT * WH;
        const int blocks = (int)((total + 255) / 256);
        corr_naive<<<dim3(blocks), dim3(256), 0, stream>>>(x0, x1, out);
    }
}